// Round 7
// baseline (308.283 us; speedup 1.0000x reference)
//
#include <hip/hip_runtime.h>

typedef __attribute__((ext_vector_type(4))) float f32x4;
typedef __attribute__((ext_vector_type(8))) short bf16x8;  // 8 bf16 = 4 VGPRs

#define HDIM 128

// fp32 -> bf16 round-to-nearest-even
__device__ __forceinline__ short f2bf(float f) {
  union { float fv; unsigned u; } v; v.fv = f;
  unsigned u = v.u;
  u += 0x7fffu + ((u >> 16) & 1u);
  return (short)(u >> 16);
}

// async global->LDS, 16B per lane: LDS dst = wave-uniform base + lane*16
__device__ __forceinline__ void gload_lds16(const float* g, float* l) {
  __builtin_amdgcn_global_load_lds(
      (const __attribute__((address_space(1))) void*)g,
      (__attribute__((address_space(3))) void*)l, 16, 0, 0);
}

// out[b][g] = sum_k h[b][k] * W[g][k] + x[b][g]
// MFMA: A = W (g), B = h^T (b), x as C-in. C/D: col=lane&15 -> b,
// row=(lane>>4)*4+reg -> g => lane's 4 accs = 4 contiguous g: float4 I/O.
//
// Round 7: deep read pipeline via global_load_lds (zero-VGPR in-flight bytes).
// Theory: R6 reads are MLP-limited (5.1 KB/CU in flight vs 9.2 KB needed for
// full BW; measured read rate sits exactly at supply). This kernel keeps
// 24-64 KB/CU in flight: h tiles DMA'd to a 2-deep LDS ring, x one tile
// ahead in regs. Each wave's ring slice (rows wave*16..+16) is loaded AND
// read only by itself => no main-loop barriers; per-wave counted vmcnt(16)
// paces the pipe (never drained to 0 mid-loop). 1 block/CU (96 KB LDS), so
// VGPRs are free real estate: launch_bounds(256,1) -- no forced buckets,
// no spills (R2/R3 lesson).
__global__ __launch_bounds__(256, 1) void lrc_pipe_kernel(
    const float* __restrict__ xp,
    const float* __restrict__ hp,
    const float* __restrict__ Wp,
    float* __restrict__ outp,
    int tiles_per_block)  // 64-row tiles per block (contiguous chunk), even, >=4
{
  __shared__ short wlds[32 * 64 * 8];   // 32 KB: W as 32 bf16 A-fragments
  __shared__ float hbuf0[64 * HDIM];    // 32 KB: h tile ring buffer 0
  __shared__ float hbuf1[64 * HDIM];    // 32 KB: h tile ring buffer 1

  const int tid  = (int)threadIdx.x;
  const int wave = tid >> 6;   // 0..3
  const int lane = tid & 63;
  const int l15  = lane & 15;
  const int lq   = lane >> 4;

  // ---- Stage W fragments in LDS (once). f = gt*4 + kt (R6-proven) ----
  #pragma unroll
  for (int i = 0; i < 8; ++i) {
    const int f  = wave * 8 + i;
    const int gt = f >> 2;
    const int kt = f & 3;
    const float* wrow = Wp + (gt * 16 + l15) * HDIM + kt * 32 + lq * 8;
    const f32x4 w0 = *(const f32x4*)(wrow);
    const f32x4 w1 = *(const f32x4*)(wrow + 4);
    bf16x8 wf;
    wf[0] = f2bf(w0[0]); wf[1] = f2bf(w0[1]); wf[2] = f2bf(w0[2]); wf[3] = f2bf(w0[3]);
    wf[4] = f2bf(w1[0]); wf[5] = f2bf(w1[1]); wf[6] = f2bf(w1[2]); wf[7] = f2bf(w1[3]);
    *(bf16x8*)(&wlds[(f * 64 + lane) * 8]) = wf;
  }
  __syncthreads();  // only barrier in the kernel

  const long tile0 = (long)blockIdx.x * tiles_per_block;
  // per-lane global sub-offset for h DMA: lanes 0-31 -> row +0 cols 4l,
  // lanes 32-63 -> row +1 cols 4(l-32); one instr = 2 rows = 1 KB
  const int hsub = (lane >> 5) * HDIM + (lane & 31) * 4;

  f32x4 xvA[8], xvB[8];  // x prefetch regs (statically indexed only)

// issue 8 global_load_lds: this wave's 16 rows of h[t] into DST (private slice)
#define ISSUE_H(DST, T) do {                                               \
    const float* gs_ = hp + ((long)(T) * 64 + wave * 16) * HDIM + hsub;    \
    _Pragma("unroll")                                                      \
    for (int i_ = 0; i_ < 8; ++i_)                                         \
      gload_lds16(gs_ + i_ * 256, (DST) + (wave * 16 + i_ * 2) * HDIM);    \
  } while (0)

// issue 8 float4 x loads into XA (regs); addresses match the out stores
#define ISSUE_X(XA, T) do {                                                \
    const float* xr_ = xp + ((long)(T) * 64 + wave * 16 + l15) * HDIM + lq * 4; \
    _Pragma("unroll")                                                      \
    for (int g_ = 0; g_ < 8; ++g_) XA[g_] = *(const f32x4*)(xr_ + g_ * 16); \
  } while (0)

// allow newest 16 VMEM ops (this step's prefetches) to stay in flight;
// everything older -- h[t], x[t], stores(t-1) -- is drained (in-order retire)
#define WAIT16 asm volatile("s_waitcnt vmcnt(16)" ::: "memory")
#define WAIT0  asm volatile("s_waitcnt vmcnt(0)"  ::: "memory")
#define SCHEDB __builtin_amdgcn_sched_barrier(0)

// compute tile T from LDS h slice SRC + x regs XA; store out
#define COMPUTE(T, SRC, XA) do {                                           \
    const float* hb_ = (SRC) + (wave * 16 + l15) * HDIM + lq * 8;          \
    bf16x8 hf_[4];                                                         \
    _Pragma("unroll")                                                      \
    for (int kt_ = 0; kt_ < 4; ++kt_) {                                    \
      const f32x4 a_ = *(const f32x4*)(hb_ + kt_ * 32);                    \
      const f32x4 b_ = *(const f32x4*)(hb_ + kt_ * 32 + 4);                \
      hf_[kt_][0] = f2bf(a_[0]); hf_[kt_][1] = f2bf(a_[1]);                \
      hf_[kt_][2] = f2bf(a_[2]); hf_[kt_][3] = f2bf(a_[3]);                \
      hf_[kt_][4] = f2bf(b_[0]); hf_[kt_][5] = f2bf(b_[1]);                \
      hf_[kt_][6] = f2bf(b_[2]); hf_[kt_][7] = f2bf(b_[3]);                \
    }                                                                      \
    float* orow_ = outp + ((long)(T) * 64 + wave * 16 + l15) * HDIM;       \
    _Pragma("unroll")                                                      \
    for (int gt_ = 0; gt_ < 8; ++gt_) {                                    \
      f32x4 acc_ = XA[gt_];                                                \
      _Pragma("unroll")                                                    \
      for (int kt_ = 0; kt_ < 4; ++kt_) {                                  \
        const bf16x8 wf_ = *(const bf16x8*)(&wlds[((gt_ * 4 + kt_) * 64 + lane) * 8]); \
        acc_ = __builtin_amdgcn_mfma_f32_16x16x32_bf16(wf_, hf_[kt_], acc_, 0, 0, 0);  \
      }                                                                    \
      *(f32x4*)(orow_ + gt_ * 16 + lq * 4) = acc_;                         \
    }                                                                      \
  } while (0)

  // ---- Prologue ----
  long t = tile0;
  ISSUE_H(hbuf0, t);
  ISSUE_X(xvA, t);

  // ---- Main loop: compute t from buf0/xvA, t+1 from buf1/xvB ----
  for (int i = 0; i + 2 < tiles_per_block; i += 2) {
    ISSUE_H(hbuf1, t + 1); ISSUE_X(xvB, t + 1);
    WAIT16; COMPUTE(t, hbuf0, xvA); SCHEDB;
    ISSUE_H(hbuf0, t + 2); ISSUE_X(xvA, t + 2);
    WAIT16; COMPUTE(t + 1, hbuf1, xvB); SCHEDB;
    t += 2;
  }
  // ---- Tail: last two tiles ----
  ISSUE_H(hbuf1, t + 1); ISSUE_X(xvB, t + 1);
  WAIT16; COMPUTE(t, hbuf0, xvA); SCHEDB;
  WAIT0;  COMPUTE(t + 1, hbuf1, xvB);

#undef ISSUE_H
#undef ISSUE_X
#undef WAIT16
#undef WAIT0
#undef SCHEDB
#undef COMPUTE
}

extern "C" void kernel_launch(void* const* d_in, const int* in_sizes, int n_in,
                              void* d_out, int out_size, void* d_ws, size_t ws_size,
                              hipStream_t stream) {
  const float* xp = (const float*)d_in[0];  // x_projected_t (B,H) fp32
  const float* hp = (const float*)d_in[1];  // h_prev        (B,H) fp32
  const float* Wp = (const float*)d_in[2];  // W_hh          (H,H) fp32
  float* op = (float*)d_out;                // h_next        (B,H) fp32

  const int B = in_sizes[0] / HDIM;         // 1048576
  const int num_tiles = B / 64;             // 16384 tiles of 64 rows
  const int grid = 512;                     // 1 block/CU resident (96 KB LDS);
  const int tpb  = num_tiles / grid;        // 32 contiguous tiles per block

  hipLaunchKernelGGL(lrc_pipe_kernel, dim3(grid), dim3(256), 0, stream,
                     xp, hp, Wp, op, tpb);
}